// Round 6
// baseline (107.129 us; speedup 1.0000x reference)
//
#include <hip/hip_runtime.h>

#define GAT_ALPHA 0.2f
#define INV_N (1.0f / 2048.0f)

typedef float f32x4 __attribute__((ext_vector_type(4)));
typedef int   i32x4 __attribute__((ext_vector_type(4)));
typedef __bf16 bf16x8 __attribute__((ext_vector_type(8)));
typedef unsigned short us8 __attribute__((ext_vector_type(8)));

__device__ __forceinline__ unsigned short f2bf(float x) {
  union { float f; unsigned u; } v; v.f = x;
  unsigned r = v.u + 0x7FFFu + ((v.u >> 16) & 1u);   // RNE
  return (unsigned short)(r >> 16);
}
__device__ __forceinline__ float lrelu(float x) {
  return fmaxf(x, 0.f) + GAT_ALPHA * fminf(x, 0.f);
}

// ---------------- k0: Wh = h @ W (f32), s1/s2, WhT in bf16 [b][f][j] ----------------
__global__ __launch_bounds__(256)
void k0_wh(const float* __restrict__ h, const float* __restrict__ W,
           const float* __restrict__ a, unsigned short* __restrict__ WhT,
           float* __restrict__ s1g, float* __restrict__ s2g)
{
  __shared__ float h_s[64][132];
  __shared__ float W_s[128][64];
  __shared__ float wt_s[64][66];
  __shared__ float a_s[128];
  const int t = threadIdx.x;
  const int b = blockIdx.y;
  const int r0 = blockIdx.x * 64;

#pragma unroll
  for (int v = 0; v < 8; ++v) {
    int c = v * 256 + t;
    int k = c >> 4, fo = (c & 15) << 2;
    *(float4*)&W_s[k][fo] = *(const float4*)&W[k * 64 + fo];
  }
#pragma unroll
  for (int v = 0; v < 8; ++v) {
    int c = v * 256 + t;
    int r = c >> 5, ko = (c & 31) << 2;
    *(float4*)&h_s[r][ko] = *(const float4*)&h[((size_t)(b * 2048 + r0 + r)) * 128 + ko];
  }
  if (t < 128) a_s[t] = a[t];
  __syncthreads();

  const int tg = t >> 4;          // 0..15
  const int tf = (t & 15) << 2;   // f base
  float acc[4][4] = {};
#pragma unroll
  for (int k4 = 0; k4 < 32; ++k4) {
    float4 hv[4];
#pragma unroll
    for (int i = 0; i < 4; ++i)
      hv[i] = *(const float4*)&h_s[i * 16 + tg][k4 * 4];
#pragma unroll
    for (int kk = 0; kk < 4; ++kk) {
      float4 wv = *(const float4*)&W_s[k4 * 4 + kk][tf];
#pragma unroll
      for (int i = 0; i < 4; ++i) {
        float hx = ((const float*)&hv[i])[kk];
        acc[i][0] = fmaf(hx, wv.x, acc[i][0]);
        acc[i][1] = fmaf(hx, wv.y, acc[i][1]);
        acc[i][2] = fmaf(hx, wv.z, acc[i][2]);
        acc[i][3] = fmaf(hx, wv.w, acc[i][3]);
      }
    }
  }
#pragma unroll
  for (int i = 0; i < 4; ++i)
#pragma unroll
    for (int j = 0; j < 4; ++j)
      wt_s[tf + j][i * 16 + tg] = acc[i][j];
  __syncthreads();

  if (t < 64) {   // s1/s2 for row r = t (f32 exact)
    float v1 = 0.f, v2 = 0.f;
#pragma unroll 8
    for (int f = 0; f < 64; ++f) {
      float w = wt_s[f][t];
      v1 = fmaf(w, a_s[f], v1);
      v2 = fmaf(w, a_s[64 + f], v2);
    }
    s1g[b * 2048 + r0 + t] = v1;
    s2g[b * 2048 + r0 + t] = v2;
  }
  {  // WhT bf16 write, [b][f][j]
    int f = t >> 2, rb = (t & 3) << 4;
    unsigned short pk[16];
#pragma unroll
    for (int i = 0; i < 16; ++i) pk[i] = f2bf(wt_s[f][rb + i]);
    size_t base = ((size_t)(b * 64 + f)) * 2048 + r0 + rb;
    *(uint4*)&WhT[base]     = *(uint4*)&pk[0];
    *(uint4*)&WhT[base + 8] = *(uint4*)&pk[8];
  }
}

// ---------------- k1: wave-per-row: denom + bitmask; cached adj loads (L3-resident) ----------------
// bit convention: word[c*4 + q] bit l  <->  j = c*256 + 4*l + q
__global__ __launch_bounds__(256)
void k1_stats(const int* __restrict__ adj, const float* __restrict__ s1g,
              const float* __restrict__ s2g, float* __restrict__ lrow,
              unsigned long long* __restrict__ gmask)
{
  const int t = threadIdx.x;
  const int l = t & 63, w = t >> 6;
  const int b = blockIdx.y;
  const int i = blockIdx.x * 4 + w;
  const size_t row = (size_t)(b * 2048 + i);
  const int* __restrict__ arow = adj + row * 2048;
  const float* __restrict__ z = s2g + b * 2048;
  unsigned long long* __restrict__ g = gmask + row * 32;

  // issue ALL adj loads first (max outstanding reads), then z
  i32x4 av[8];
#pragma unroll
  for (int c = 0; c < 8; ++c) av[c] = *(const i32x4*)&arow[c * 256 + 4 * l];
  float4 zv[8];
#pragma unroll
  for (int c = 0; c < 8; ++c) zv[c] = *(const float4*)&z[c * 256 + 4 * l];

  unsigned pb = 0;           // 4 pred bits per chunk, 8 chunks
#pragma unroll
  for (int c = 0; c < 8; ++c) {
    const bool p0 = av[c].x > 0, p1 = av[c].y > 0, p2 = av[c].z > 0, p3 = av[c].w > 0;
    unsigned long long b0 = __ballot(p0), b1 = __ballot(p1);
    unsigned long long b2 = __ballot(p2), b3 = __ballot(p3);
    if (l == 0) {
      ulonglong2 u0; u0.x = b0; u0.y = b1;
      ulonglong2 u1; u1.x = b2; u1.y = b3;
      *(ulonglong2*)&g[c * 4]     = u0;
      *(ulonglong2*)&g[c * 4 + 2] = u1;
    }
    pb |= (unsigned(p0) | (unsigned(p1) << 1) | (unsigned(p2) << 2) | (unsigned(p3) << 3)) << (c * 4);
  }

  const float s1v = s1g[row];
  float sum = 0.f;
#pragma unroll
  for (int c = 0; c < 8; ++c) {
    sum += ((pb >> (c * 4)) & 1u) ? __expf(lrelu(s1v + zv[c].x)) : 0.f;
    sum += ((pb >> (c * 4 + 1)) & 1u) ? __expf(lrelu(s1v + zv[c].y)) : 0.f;
    sum += ((pb >> (c * 4 + 2)) & 1u) ? __expf(lrelu(s1v + zv[c].z)) : 0.f;
    sum += ((pb >> (c * 4 + 3)) & 1u) ? __expf(lrelu(s1v + zv[c].w)) : 0.f;
  }
#pragma unroll
  for (int o = 32; o > 0; o >>= 1) sum += __shfl_xor(sum, o);

  if (l == 0) lrow[row] = sum;
}

// ---------------- k2_het: role W (blockIdx.x even) = pure att stream writer;
//                  role P (blockIdx.x odd)  = pure PV MFMA -> hout (ELU) ----------------
__global__ __launch_bounds__(256)
void k2_het(const unsigned long long* __restrict__ gmask,
            const unsigned short* __restrict__ WhT,
            const float* __restrict__ s1g, const float* __restrict__ s2g,
            const float* __restrict__ lrow,
            float* __restrict__ hout, float* __restrict__ att)
{
  __shared__ float z_s[2048];
  __shared__ float s1_s[32], il_s[32];
  __shared__ unsigned long long bm_s[32][32];   // W-role only

  const int t = threadIdx.x;
  const int b = blockIdx.y;
  const int role = blockIdx.x & 1;              // 0 = W (att write), 1 = P (PV)
  const int r0 = (blockIdx.x >> 1) * 32;
  const size_t rowb = (size_t)(b * 2048 + r0);

  *(float4*)&z_s[t * 8]     = *(const float4*)&s2g[b * 2048 + t * 8];
  *(float4*)&z_s[t * 8 + 4] = *(const float4*)&s2g[b * 2048 + t * 8 + 4];
  if (t < 32) {
    float L = lrow[rowb + t];
    s1_s[t] = s1g[rowb + t];
    il_s[t] = (L > 0.f) ? 1.f / L : -1.f;   // -1 sentinel: no neighbors -> uniform 1/N
  }
  if (role == 0) {  // stage all 32 ballot words per row
    const int rr = t >> 3, wq = (t & 7) << 2;
    ulonglong2 v0 = *(const ulonglong2*)&gmask[(rowb + rr) * 32 + wq];
    ulonglong2 v1 = *(const ulonglong2*)&gmask[(rowb + rr) * 32 + wq + 2];
    bm_s[rr][wq] = v0.x; bm_s[rr][wq + 1] = v0.y;
    bm_s[rr][wq + 2] = v1.x; bm_s[rr][wq + 3] = v1.y;
  }
  __syncthreads();

  if (role == 0) {
    // ---- W: dependency-free store stream, no loop barriers, no MFMA ----
    const int rbase = t >> 5;            // 0..7
    const int jj = (t & 31) << 2;        // 0..124
#pragma unroll
    for (int it = 0; it < 4; ++it) {
      const int rr = rbase + (it << 3);  // row 0..31
      const float s1v = s1_s[rr], il = il_s[rr];
      const bool uni = (il < 0.f);
      float* __restrict__ arow = att + (rowb + rr) * 2048;
#pragma unroll
      for (int j0 = 0; j0 < 2048; j0 += 128) {
        const int j = j0 + jj;
        const int c4 = (j >> 8) << 2;
        const int pos = (j & 255) >> 2;
        const unsigned long long w0 = bm_s[rr][c4 + 0];
        const unsigned long long w1 = bm_s[rr][c4 + 1];
        const unsigned long long w2 = bm_s[rr][c4 + 2];
        const unsigned long long w3 = bm_s[rr][c4 + 3];
        const float4 zv = *(const float4*)&z_s[j];
        f32x4 o;
#define PW(dst, zz, wq)                                             \
        { float e = __expf(lrelu(s1v + (zz))) * il;                 \
          dst = uni ? INV_N : ((((wq) >> pos) & 1ull) ? e : 0.f); }
        PW(o[0], zv.x, w0) PW(o[1], zv.y, w1) PW(o[2], zv.z, w2) PW(o[3], zv.w, w3)
#undef PW
        __builtin_nontemporal_store(o, (f32x4*)&arow[j]);
      }
    }
  } else {
    // ---- P: register-fragment PV (R4-verified), no att stores ----
    const int w  = t >> 6, l = t & 63;
    const int ln = l & 15, lg = l >> 4;
    const int rt = (w & 1) << 4;
    const int fp = w >> 1;                    // f-tile pair: tiles 2fp, 2fp+1
    const int row = rt + ln;

    const float s1v = s1_s[row];
    const float il  = il_s[row];
    const bool uni  = (il < 0.f);
    const unsigned long long* __restrict__ gm = gmask + (rowb + row) * 32;
    const unsigned short* __restrict__ wb0 = WhT + ((size_t)(b * 64 + 2 * fp * 16 + ln)) * 2048;
    const unsigned short* __restrict__ wb1 = wb0 + 16 * 2048;

    f32x4 acc0 = {0.f, 0.f, 0.f, 0.f};
    f32x4 acc1 = {0.f, 0.f, 0.f, 0.f};

    unsigned long long w0 = 0, w1 = 0, w2 = 0, w3 = 0;
    for (int j0 = 0; j0 < 2048; j0 += 128) {
      if ((j0 & 255) == 0) {   // refresh ballot words per 256-j chunk
        const int c = j0 >> 8;
        ulonglong2 u0 = *(const ulonglong2*)&gm[c * 4];
        ulonglong2 u1 = *(const ulonglong2*)&gm[c * 4 + 2];
        w0 = u0.x; w1 = u0.y; w2 = u1.x; w3 = u1.y;
      }
#pragma unroll
      for (int ks = 0; ks < 4; ++ks) {
        const int jb = j0 + ks * 32 + lg * 8;
        const int pos0 = (jb & 255) >> 2;     // base bit position, never wraps
        const float4 za = *(const float4*)&z_s[jb];
        const float4 zb = *(const float4*)&z_s[jb + 4];
        float o[8];
#define PE(dst, zz, m)                                                     \
        { float e = __expf(lrelu(s1v + (zz))) * il;                        \
          const unsigned long long wq = ((m) & 3) == 0 ? w0 :              \
                                        ((m) & 3) == 1 ? w1 :              \
                                        ((m) & 3) == 2 ? w2 : w3;          \
          const bool on = ((wq >> (pos0 + ((m) >> 2))) & 1ull) != 0;       \
          dst = uni ? INV_N : (on ? e : 0.f); }
        PE(o[0], za.x, 0) PE(o[1], za.y, 1) PE(o[2], za.z, 2) PE(o[3], za.w, 3)
        PE(o[4], zb.x, 4) PE(o[5], zb.y, 5) PE(o[6], zb.z, 6) PE(o[7], zb.w, 7)
#undef PE
        bf16x8 af;
#pragma unroll
        for (int m = 0; m < 8; ++m) af[m] = (__bf16)o[m];
        union { us8 u; bf16x8 v; } b0c, b1c;
        b0c.u = *(const us8*)&wb0[jb];
        b1c.u = *(const us8*)&wb1[jb];
        acc0 = __builtin_amdgcn_mfma_f32_16x16x32_bf16(af, b0c.v, acc0, 0, 0, 0);
        acc1 = __builtin_amdgcn_mfma_f32_16x16x32_bf16(af, b1c.v, acc1, 0, 0, 0);
      }
    }

    // epilogue: ELU. C/D layout: col(N=f)=lane&15, row(M)=4*(lane>>4)+reg
#pragma unroll
    for (int q = 0; q < 4; ++q) {
      const int rr = rt + lg * 4 + q;
      {
        float x = acc0[q];
        hout[(rowb + rr) * 64 + (2 * fp) * 16 + ln] = (x > 0.f) ? x : expm1f(x);
      }
      {
        float x = acc1[q];
        hout[(rowb + rr) * 64 + (2 * fp + 1) * 16 + ln] = (x > 0.f) ? x : expm1f(x);
      }
    }
  }
}

extern "C" void kernel_launch(void* const* d_in, const int* in_sizes, int n_in,
                              void* d_out, int out_size, void* d_ws, size_t ws_size,
                              hipStream_t stream)
{
  const float* h   = (const float*)d_in[0];
  const int*   adj = (const int*)d_in[1];
  const float* W   = (const float*)d_in[2];
  const float* a   = (const float*)d_in[3];
  float* hout = (float*)d_out;
  float* att  = hout + (size_t)8 * 2048 * 64;

  char* ws = (char*)d_ws;
  unsigned short* WhT = (unsigned short*)ws;                    // 2 MB
  float* s1 = (float*)(ws + (size_t)(2u << 20));                // 64 KB each
  float* s2 = s1 + 16384;
  float* lr = s2 + 16384;
  unsigned long long* gmask =
      (unsigned long long*)(ws + (size_t)(2u << 20) + 3 * 65536); // 4 MB

  k0_wh   <<<dim3(32, 8),  256, 0, stream>>>(h, W, a, WhT, s1, s2);
  k1_stats<<<dim3(512, 8), 256, 0, stream>>>(adj, s1, s2, lr, gmask);
  k2_het  <<<dim3(128, 8), 256, 0, stream>>>(gmask, WhT, s1, s2, lr, hout, att);
}

// Round 7
// 91.988 us; speedup vs baseline: 1.1646x; 1.1646x over previous
//
#include <hip/hip_runtime.h>

#define GAT_ALPHA 0.2f
#define INV_N (1.0f / 2048.0f)

typedef float f32x4 __attribute__((ext_vector_type(4)));
typedef __bf16 bf16x8 __attribute__((ext_vector_type(8)));
typedef unsigned short us8 __attribute__((ext_vector_type(8)));
typedef unsigned short us4 __attribute__((ext_vector_type(4)));

__device__ __forceinline__ unsigned short f2bf(float x) {
  union { float f; unsigned u; } v; v.f = x;
  unsigned r = v.u + 0x7FFFu + ((v.u >> 16) & 1u);   // RNE
  return (unsigned short)(r >> 16);
}
__device__ __forceinline__ float lrelu(float x) {
  return fmaxf(x, 0.f) + GAT_ALPHA * fminf(x, 0.f);
}
__device__ __forceinline__ void lgkm_barrier() {
  asm volatile("s_waitcnt lgkmcnt(0)" ::: "memory");
  __builtin_amdgcn_s_barrier();
  __builtin_amdgcn_sched_barrier(0);
}

// ---------------- k0: Wh = h @ W (f32), s1/s2, WhT in bf16 [b][f][j] ----------------
__global__ __launch_bounds__(256)
void k0_wh(const float* __restrict__ h, const float* __restrict__ W,
           const float* __restrict__ a, unsigned short* __restrict__ WhT,
           float* __restrict__ s1g, float* __restrict__ s2g)
{
  __shared__ float h_s[64][132];
  __shared__ float W_s[128][64];
  __shared__ float wt_s[64][66];
  __shared__ float a_s[128];
  const int t = threadIdx.x;
  const int b = blockIdx.y;
  const int r0 = blockIdx.x * 64;

#pragma unroll
  for (int v = 0; v < 8; ++v) {
    int c = v * 256 + t;
    int k = c >> 4, fo = (c & 15) << 2;
    *(float4*)&W_s[k][fo] = *(const float4*)&W[k * 64 + fo];
  }
#pragma unroll
  for (int v = 0; v < 8; ++v) {
    int c = v * 256 + t;
    int r = c >> 5, ko = (c & 31) << 2;
    *(float4*)&h_s[r][ko] = *(const float4*)&h[((size_t)(b * 2048 + r0 + r)) * 128 + ko];
  }
  if (t < 128) a_s[t] = a[t];
  __syncthreads();

  const int tg = t >> 4;          // 0..15
  const int tf = (t & 15) << 2;   // f base
  float acc[4][4] = {};
#pragma unroll
  for (int k4 = 0; k4 < 32; ++k4) {
    float4 hv[4];
#pragma unroll
    for (int i = 0; i < 4; ++i)
      hv[i] = *(const float4*)&h_s[i * 16 + tg][k4 * 4];
#pragma unroll
    for (int kk = 0; kk < 4; ++kk) {
      float4 wv = *(const float4*)&W_s[k4 * 4 + kk][tf];
#pragma unroll
      for (int i = 0; i < 4; ++i) {
        float hx = ((const float*)&hv[i])[kk];
        acc[i][0] = fmaf(hx, wv.x, acc[i][0]);
        acc[i][1] = fmaf(hx, wv.y, acc[i][1]);
        acc[i][2] = fmaf(hx, wv.z, acc[i][2]);
        acc[i][3] = fmaf(hx, wv.w, acc[i][3]);
      }
    }
  }
#pragma unroll
  for (int i = 0; i < 4; ++i)
#pragma unroll
    for (int j = 0; j < 4; ++j)
      wt_s[tf + j][i * 16 + tg] = acc[i][j];
  __syncthreads();

  if (t < 64) {   // s1/s2 for row r = t (f32 exact)
    float v1 = 0.f, v2 = 0.f;
#pragma unroll 8
    for (int f = 0; f < 64; ++f) {
      float w = wt_s[f][t];
      v1 = fmaf(w, a_s[f], v1);
      v2 = fmaf(w, a_s[64 + f], v2);
    }
    s1g[b * 2048 + r0 + t] = v1;
    s2g[b * 2048 + r0 + t] = v2;
  }
  {  // WhT bf16 write, [b][f][j]
    int f = t >> 2, rb = (t & 3) << 4;
    unsigned short pk[16];
#pragma unroll
    for (int i = 0; i < 16; ++i) pk[i] = f2bf(wt_s[f][rb + i]);
    size_t base = ((size_t)(b * 64 + f)) * 2048 + r0 + rb;
    *(uint4*)&WhT[base]     = *(uint4*)&pk[0];
    *(uint4*)&WhT[base + 8] = *(uint4*)&pk[8];
  }
}

// ---------------- k1: block-per-row (R2 shape), denom + bitmask; cached loads; no max pass ----------------
// bit convention: word[c*4 + q] bit l  <->  j = c*256 + 4*l + q
__global__ __launch_bounds__(256)
void k1_stats(const int* __restrict__ adj, const float* __restrict__ s1g,
              const float* __restrict__ s2g, float* __restrict__ lrow,
              unsigned long long* __restrict__ gmask)
{
  const int t = threadIdx.x;
  const int l = t & 63, wv = t >> 6;
  const int i = blockIdx.x, b = blockIdx.y;
  const size_t row = (size_t)(b * 2048 + i);

  const int4 a0 = *(const int4*)&adj[row * 2048 + 4 * t];
  const int4 a1 = *(const int4*)&adj[row * 2048 + 1024 + 4 * t];
  const float4 z0 = *(const float4*)&s2g[b * 2048 + 4 * t];
  const float4 z1 = *(const float4*)&s2g[b * 2048 + 1024 + 4 * t];

  unsigned long long m00 = __ballot(a0.x > 0), m01 = __ballot(a0.y > 0);
  unsigned long long m02 = __ballot(a0.z > 0), m03 = __ballot(a0.w > 0);
  unsigned long long m10 = __ballot(a1.x > 0), m11 = __ballot(a1.y > 0);
  unsigned long long m12 = __ballot(a1.z > 0), m13 = __ballot(a1.w > 0);
  if (l == 0) {
    unsigned long long* g = gmask + row * 32;
    ulonglong2 p0; p0.x = m00; p0.y = m01;
    ulonglong2 p1; p1.x = m02; p1.y = m03;
    ulonglong2 p2; p2.x = m10; p2.y = m11;
    ulonglong2 p3; p3.x = m12; p3.y = m13;
    *(ulonglong2*)&g[wv * 4]          = p0;
    *(ulonglong2*)&g[wv * 4 + 2]      = p1;
    *(ulonglong2*)&g[16 + wv * 4]     = p2;
    *(ulonglong2*)&g[16 + wv * 4 + 2] = p3;
  }

  const float s1v = s1g[row];
  float sum = 0.f;
  sum += (a0.x > 0) ? __expf(lrelu(s1v + z0.x)) : 0.f;
  sum += (a0.y > 0) ? __expf(lrelu(s1v + z0.y)) : 0.f;
  sum += (a0.z > 0) ? __expf(lrelu(s1v + z0.z)) : 0.f;
  sum += (a0.w > 0) ? __expf(lrelu(s1v + z0.w)) : 0.f;
  sum += (a1.x > 0) ? __expf(lrelu(s1v + z1.x)) : 0.f;
  sum += (a1.y > 0) ? __expf(lrelu(s1v + z1.y)) : 0.f;
  sum += (a1.z > 0) ? __expf(lrelu(s1v + z1.z)) : 0.f;
  sum += (a1.w > 0) ? __expf(lrelu(s1v + z1.w)) : 0.f;
#pragma unroll
  for (int o = 32; o > 0; o >>= 1) sum += __shfl_xor(sum, o);
  __shared__ float red2[4];
  if (l == 0) red2[wv] = sum;
  __syncthreads();
  if (t == 0) lrow[row] = red2[0] + red2[1] + red2[2] + red2[3];
}

// ---------------- k2: att write (f32, cached) + partial PV MFMA; 4-way j-split ----------------
// R2 skeleton: all 256 threads compute att for 32 rows x 128 j per iter, stash bf16 in
// att_s, lgkm barriers, MFMA A from att_s, B DIRECT from L2-resident WhT (R4-verified).
__global__ __launch_bounds__(256)
void k2_att_pv(const unsigned long long* __restrict__ gmask,
               const unsigned short* __restrict__ WhT,
               const float* __restrict__ s1g, const float* __restrict__ s2g,
               const float* __restrict__ lrow,
               float* __restrict__ pp, float* __restrict__ att)
{
  __shared__ unsigned short att_s[32][136];     // bf16, stride 272 B
  __shared__ unsigned long long bm_s[32][8];    // 2 chunks x 4 words per row
  __shared__ float s1_s[32], il_s[32];

  const int t = threadIdx.x;
  const int b = blockIdx.z;
  const int jh = blockIdx.y;            // 0..3
  const int jb = jh << 9;               // j base (512-wide slice)
  const int r0 = blockIdx.x * 32;
  const size_t rowb = (size_t)(b * 2048 + r0);

  {
    const int rr = t >> 3, wq = t & 7;
    bm_s[rr][wq] = gmask[(rowb + rr) * 32 + jh * 8 + wq];
  }
  if (t < 32) {
    float L = lrow[rowb + t];
    s1_s[t] = s1g[rowb + t];
    il_s[t] = (L > 0.f) ? 1.f / L : -1.f;   // -1 sentinel: no neighbors -> uniform 1/N
  }
  __syncthreads();

  const int w  = t >> 6, l = t & 63;
  const int ln = l & 15, lg = l >> 4;
  const int rt  = (w & 1) << 4;     // row tile 0/16
  const int ft0 = (w >> 1) << 1;    // f-tile pair base (0 or 2)
  const unsigned short* __restrict__ wb0 = WhT + ((size_t)(b * 64 + ft0 * 16 + ln)) * 2048;
  const unsigned short* __restrict__ wb1 = wb0 + 16 * 2048;
  f32x4 acc0 = {0.f, 0.f, 0.f, 0.f};
  f32x4 acc1 = {0.f, 0.f, 0.f, 0.f};

  for (int j0 = jb; j0 < jb + 512; j0 += 128) {
    // attention values: compute f32, write global (cached), stash bf16 in LDS
#pragma unroll
    for (int it = 0; it < 4; ++it) {
      const int r  = (t >> 5) + (it << 3);
      const int jj = (t & 31) << 2;
      const int j  = j0 + jj;
      const float s1v = s1_s[r], il = il_s[r];
      const bool uni = (il < 0.f);
      const int lc4 = ((j >> 8) & 1) << 2;
      const int pos = (j & 255) >> 2;
      const unsigned long long w0 = bm_s[r][lc4 + 0];
      const unsigned long long w1 = bm_s[r][lc4 + 1];
      const unsigned long long w2 = bm_s[r][lc4 + 2];
      const unsigned long long w3 = bm_s[r][lc4 + 3];
      const float4 zv = *(const float4*)&s2g[b * 2048 + j];
      float4 o;
#define PW(dst, zz, wq)                                             \
      { float e = __expf(lrelu(s1v + (zz))) * il;                   \
        dst = uni ? INV_N : ((((wq) >> pos) & 1ull) ? e : 0.f); }
      PW(o.x, zv.x, w0) PW(o.y, zv.y, w1) PW(o.z, zv.z, w2) PW(o.w, zv.w, w3)
#undef PW
      *(float4*)&att[(rowb + r) * 2048 + j] = o;
      us4 pk;
      pk.x = f2bf(o.x); pk.y = f2bf(o.y); pk.z = f2bf(o.z); pk.w = f2bf(o.w);
      *(us4*)&att_s[r][jj] = pk;
    }
    lgkm_barrier();   // publish att_s; att global stores stay in flight
    // PV: A from att_s, B direct from L2-hot WhT; same k-permutation both operands
#pragma unroll
    for (int ks = 0; ks < 4; ++ks) {
      const int kk = ks * 32 + lg * 8;
      union { us8 u; bf16x8 v; } a0c, b0c, b1c;
      a0c.u = *(const us8*)&att_s[rt + ln][kk];
      b0c.u = *(const us8*)&wb0[j0 + kk];
      b1c.u = *(const us8*)&wb1[j0 + kk];
      acc0 = __builtin_amdgcn_mfma_f32_16x16x32_bf16(a0c.v, b0c.v, acc0, 0, 0, 0);
      acc1 = __builtin_amdgcn_mfma_f32_16x16x32_bf16(a0c.v, b1c.v, acc1, 0, 0, 0);
    }
    lgkm_barrier();   // LDS reads done before next overwrite
  }

  // partial write. C/D layout: col(N=f)=lane&15, row(M)=4*(lane>>4)+reg
  float* __restrict__ ppj = pp + (size_t)jh * 8 * 2048 * 64;
#pragma unroll
  for (int q = 0; q < 4; ++q) {
    const int rr = rt + lg * 4 + q;
    ppj[(rowb + rr) * 64 + ft0 * 16 + ln]       = acc0[q];
    ppj[(rowb + rr) * 64 + (ft0 + 1) * 16 + ln] = acc1[q];
  }
}

// ---------------- k3: hout = elu(pp0+pp1+pp2+pp3) ----------------
__global__ __launch_bounds__(256)
void k3_elu(const float* __restrict__ pp, float* __restrict__ hout)
{
  const size_t n = (size_t)8 * 2048 * 64;
  const size_t idx = ((size_t)blockIdx.x * 256 + threadIdx.x) * 4;
  float4 a0 = *(const float4*)&pp[idx];
  float4 a1 = *(const float4*)&pp[idx + n];
  float4 a2 = *(const float4*)&pp[idx + 2 * n];
  float4 a3 = *(const float4*)&pp[idx + 3 * n];
  float4 o;
  float x;
  x = (a0.x + a1.x) + (a2.x + a3.x); o.x = (x > 0.f) ? x : expm1f(x);
  x = (a0.y + a1.y) + (a2.y + a3.y); o.y = (x > 0.f) ? x : expm1f(x);
  x = (a0.z + a1.z) + (a2.z + a3.z); o.z = (x > 0.f) ? x : expm1f(x);
  x = (a0.w + a1.w) + (a2.w + a3.w); o.w = (x > 0.f) ? x : expm1f(x);
  *(float4*)&hout[idx] = o;
}

extern "C" void kernel_launch(void* const* d_in, const int* in_sizes, int n_in,
                              void* d_out, int out_size, void* d_ws, size_t ws_size,
                              hipStream_t stream)
{
  const float* h   = (const float*)d_in[0];
  const int*   adj = (const int*)d_in[1];
  const float* W   = (const float*)d_in[2];
  const float* a   = (const float*)d_in[3];
  float* hout = (float*)d_out;
  float* att  = hout + (size_t)8 * 2048 * 64;

  char* ws = (char*)d_ws;
  unsigned short* WhT = (unsigned short*)ws;                    // 2 MB
  float* s1 = (float*)(ws + (size_t)(2u << 20));                // 64 KB each
  float* s2 = s1 + 16384;
  float* lr = s2 + 16384;
  unsigned long long* gmask =
      (unsigned long long*)(ws + (size_t)(2u << 20) + 3 * 65536); // 4 MB
  float* pp = (float*)(ws + (size_t)(2u << 20) + 3 * 65536 + (4u << 20)); // 4x4 MB

  k0_wh    <<<dim3(32, 8),    256, 0, stream>>>(h, W, a, WhT, s1, s2);
  k1_stats <<<dim3(2048, 8),  256, 0, stream>>>(adj, s1, s2, lr, gmask);
  k2_att_pv<<<dim3(64, 4, 8), 256, 0, stream>>>(gmask, WhT, s1, s2, lr, pp, att);
  k3_elu   <<<dim3(1024),     256, 0, stream>>>(pp, hout);
}

// Round 8
// 72.880 us; speedup vs baseline: 1.4699x; 1.2622x over previous
//
#include <hip/hip_runtime.h>

#define GAT_ALPHA 0.2f
#define INV_N (1.0f / 2048.0f)

typedef float f32x4 __attribute__((ext_vector_type(4)));
typedef __bf16 bf16x8 __attribute__((ext_vector_type(8)));
typedef unsigned short us8 __attribute__((ext_vector_type(8)));
typedef unsigned short us4 __attribute__((ext_vector_type(4)));

__device__ __forceinline__ unsigned short f2bf(float x) {
  union { float f; unsigned u; } v; v.f = x;
  unsigned r = v.u + 0x7FFFu + ((v.u >> 16) & 1u);   // RNE
  return (unsigned short)(r >> 16);
}
__device__ __forceinline__ float lrelu(float x) {
  return fmaxf(x, 0.f) + GAT_ALPHA * fminf(x, 0.f);
}
__device__ __forceinline__ void lgkm_barrier() {
  asm volatile("s_waitcnt lgkmcnt(0)" ::: "memory");
  __builtin_amdgcn_s_barrier();
  __builtin_amdgcn_sched_barrier(0);
}

// ---------------- k0: Wh = h @ W (f32), s1/s2, WhT in bf16 [b][f][j] ----------------
__global__ __launch_bounds__(256)
void k0_wh(const float* __restrict__ h, const float* __restrict__ W,
           const float* __restrict__ a, unsigned short* __restrict__ WhT,
           float* __restrict__ s1g, float* __restrict__ s2g)
{
  __shared__ float h_s[64][132];
  __shared__ float W_s[128][64];
  __shared__ float wt_s[64][66];
  __shared__ float a_s[128];
  const int t = threadIdx.x;
  const int b = blockIdx.y;
  const int r0 = blockIdx.x * 64;

#pragma unroll
  for (int v = 0; v < 8; ++v) {
    int c = v * 256 + t;
    int k = c >> 4, fo = (c & 15) << 2;
    *(float4*)&W_s[k][fo] = *(const float4*)&W[k * 64 + fo];
  }
#pragma unroll
  for (int v = 0; v < 8; ++v) {
    int c = v * 256 + t;
    int r = c >> 5, ko = (c & 31) << 2;
    *(float4*)&h_s[r][ko] = *(const float4*)&h[((size_t)(b * 2048 + r0 + r)) * 128 + ko];
  }
  if (t < 128) a_s[t] = a[t];
  __syncthreads();

  const int tg = t >> 4;          // 0..15
  const int tf = (t & 15) << 2;   // f base
  float acc[4][4] = {};
#pragma unroll
  for (int k4 = 0; k4 < 32; ++k4) {
    float4 hv[4];
#pragma unroll
    for (int i = 0; i < 4; ++i)
      hv[i] = *(const float4*)&h_s[i * 16 + tg][k4 * 4];
#pragma unroll
    for (int kk = 0; kk < 4; ++kk) {
      float4 wv = *(const float4*)&W_s[k4 * 4 + kk][tf];
#pragma unroll
      for (int i = 0; i < 4; ++i) {
        float hx = ((const float*)&hv[i])[kk];
        acc[i][0] = fmaf(hx, wv.x, acc[i][0]);
        acc[i][1] = fmaf(hx, wv.y, acc[i][1]);
        acc[i][2] = fmaf(hx, wv.z, acc[i][2]);
        acc[i][3] = fmaf(hx, wv.w, acc[i][3]);
      }
    }
  }
#pragma unroll
  for (int i = 0; i < 4; ++i)
#pragma unroll
    for (int j = 0; j < 4; ++j)
      wt_s[tf + j][i * 16 + tg] = acc[i][j];
  __syncthreads();

  if (t < 64) {   // s1/s2 for row r = t (f32 exact)
    float v1 = 0.f, v2 = 0.f;
#pragma unroll 8
    for (int f = 0; f < 64; ++f) {
      float w = wt_s[f][t];
      v1 = fmaf(w, a_s[f], v1);
      v2 = fmaf(w, a_s[64 + f], v2);
    }
    s1g[b * 2048 + r0 + t] = v1;
    s2g[b * 2048 + r0 + t] = v2;
  }
  {  // WhT bf16 write, [b][f][j]
    int f = t >> 2, rb = (t & 3) << 4;
    unsigned short pk[16];
#pragma unroll
    for (int i = 0; i < 16; ++i) pk[i] = f2bf(wt_s[f][rb + i]);
    size_t base = ((size_t)(b * 64 + f)) * 2048 + r0 + rb;
    *(uint4*)&WhT[base]     = *(uint4*)&pk[0];
    *(uint4*)&WhT[base + 8] = *(uint4*)&pk[8];
  }
}

// ---------------- k1: block-per-row (R2 shape), denom + bitmask; cached loads; no max pass ----------------
// bit convention: word[c*4 + q] bit l  <->  j = c*256 + 4*l + q
__global__ __launch_bounds__(256)
void k1_stats(const int* __restrict__ adj, const float* __restrict__ s1g,
              const float* __restrict__ s2g, float* __restrict__ lrow,
              unsigned long long* __restrict__ gmask)
{
  const int t = threadIdx.x;
  const int l = t & 63, wv = t >> 6;
  const int i = blockIdx.x, b = blockIdx.y;
  const size_t row = (size_t)(b * 2048 + i);

  const int4 a0 = *(const int4*)&adj[row * 2048 + 4 * t];
  const int4 a1 = *(const int4*)&adj[row * 2048 + 1024 + 4 * t];
  const float4 z0 = *(const float4*)&s2g[b * 2048 + 4 * t];
  const float4 z1 = *(const float4*)&s2g[b * 2048 + 1024 + 4 * t];

  unsigned long long m00 = __ballot(a0.x > 0), m01 = __ballot(a0.y > 0);
  unsigned long long m02 = __ballot(a0.z > 0), m03 = __ballot(a0.w > 0);
  unsigned long long m10 = __ballot(a1.x > 0), m11 = __ballot(a1.y > 0);
  unsigned long long m12 = __ballot(a1.z > 0), m13 = __ballot(a1.w > 0);
  if (l == 0) {
    unsigned long long* g = gmask + row * 32;
    ulonglong2 p0; p0.x = m00; p0.y = m01;
    ulonglong2 p1; p1.x = m02; p1.y = m03;
    ulonglong2 p2; p2.x = m10; p2.y = m11;
    ulonglong2 p3; p3.x = m12; p3.y = m13;
    *(ulonglong2*)&g[wv * 4]          = p0;
    *(ulonglong2*)&g[wv * 4 + 2]      = p1;
    *(ulonglong2*)&g[16 + wv * 4]     = p2;
    *(ulonglong2*)&g[16 + wv * 4 + 2] = p3;
  }

  const float s1v = s1g[row];
  float sum = 0.f;
  sum += (a0.x > 0) ? __expf(lrelu(s1v + z0.x)) : 0.f;
  sum += (a0.y > 0) ? __expf(lrelu(s1v + z0.y)) : 0.f;
  sum += (a0.z > 0) ? __expf(lrelu(s1v + z0.z)) : 0.f;
  sum += (a0.w > 0) ? __expf(lrelu(s1v + z0.w)) : 0.f;
  sum += (a1.x > 0) ? __expf(lrelu(s1v + z1.x)) : 0.f;
  sum += (a1.y > 0) ? __expf(lrelu(s1v + z1.y)) : 0.f;
  sum += (a1.z > 0) ? __expf(lrelu(s1v + z1.z)) : 0.f;
  sum += (a1.w > 0) ? __expf(lrelu(s1v + z1.w)) : 0.f;
#pragma unroll
  for (int o = 32; o > 0; o >>= 1) sum += __shfl_xor(sum, o);
  __shared__ float red2[4];
  if (l == 0) red2[wv] = sum;
  __syncthreads();
  if (t == 0) lrow[row] = red2[0] + red2[1] + red2[2] + red2[3];
}

// ---------------- k2: attention write (nt f32) + fused partial h_out via bf16 MFMA ----------------
// EXACT R2 structure (j-split 2-way, wh_s reg->LDS staging with T14 early loads,
// att_s bf16 stash, lgkm barriers). Only deltas: no mrow, nt att stores.
__global__ __launch_bounds__(256)
void k2_main(const unsigned long long* __restrict__ gmask,
             const unsigned short* __restrict__ WhT,
             const float* __restrict__ s1g, const float* __restrict__ s2g,
             const float* __restrict__ lrow,
             float* __restrict__ pp0, float* __restrict__ pp1,
             float* __restrict__ att)
{
  __shared__ unsigned short att_s[32][136];  // bf16, stride 272B
  __shared__ unsigned short wh_s[64][136];   // bf16, [f][k]
  __shared__ unsigned long long bm_s[32][16];
  __shared__ float s1_s[32], il_s[32];

  const int t = threadIdx.x;
  const int b = blockIdx.z;
  const int jh = blockIdx.y;
  const int jb = jh << 10;
  const int r0 = blockIdx.x * 32;
  const size_t rowb = (size_t)(b * 2048 + r0);

  {
    int rr = t >> 3, wq = (t & 7) << 1;
    ulonglong2 v = *(const ulonglong2*)&gmask[(rowb + rr) * 32 + jh * 16 + wq];
    bm_s[rr][wq] = v.x; bm_s[rr][wq + 1] = v.y;
  }
  if (t < 32) {
    float L = lrow[rowb + t];
    s1_s[t] = s1g[rowb + t];
    il_s[t] = (L > 0.f) ? 1.f / L : -1.f;   // -1 sentinel: no-neighbor row -> uniform 1/N
  }
  __syncthreads();

  const int w  = t >> 6, l = t & 63;
  const int rt  = (w & 1) << 4;     // row tile 0/16
  const int ft0 = (w >> 1) << 1;    // f-tile pair base (0 or 2)
  const int ln = l & 15, lg = l >> 4;
  f32x4 acc0 = {0.f, 0.f, 0.f, 0.f};
  f32x4 acc1 = {0.f, 0.f, 0.f, 0.f};

  const int ff = t >> 4, ko = (t & 15) << 3;   // staging coords (4 rounds of 256)

  for (int j0 = jb; j0 < jb + 1024; j0 += 128) {
    // T14: issue WhT loads early, write to LDS late (hide L2 latency under att VALU)
    uint4 wreg[4];
#pragma unroll
    for (int v = 0; v < 4; ++v)
      wreg[v] = *(const uint4*)&WhT[((size_t)(b * 64 + (v * 16 + ff))) * 2048 + j0 + ko];

    // attention values: compute f32, write global nt (stays in flight), stash bf16 in LDS
#pragma unroll
    for (int it = 0; it < 4; ++it) {
      const int r  = (t >> 5) + (it << 3);
      const int jj = (t & 31) << 2;
      const int j  = j0 + jj;
      const float s1v = s1_s[r], il = il_s[r];
      const bool uni = (il < 0.f);
      const int lc4 = ((j >> 8) & 3) << 2;
      const int pos = (j & 255) >> 2;
      const unsigned long long w0 = bm_s[r][lc4 + 0];
      const unsigned long long w1 = bm_s[r][lc4 + 1];
      const unsigned long long w2 = bm_s[r][lc4 + 2];
      const unsigned long long w3 = bm_s[r][lc4 + 3];
      const float4 zv = *(const float4*)&s2g[b * 2048 + j];
      f32x4 o;
#define PW(dst, zz, wq)                                             \
      { float e = __expf(lrelu(s1v + (zz))) * il;                   \
        dst = uni ? INV_N : ((((wq) >> pos) & 1ull) ? e : 0.f); }
      PW(o[0], zv.x, w0) PW(o[1], zv.y, w1) PW(o[2], zv.z, w2) PW(o[3], zv.w, w3)
#undef PW
      __builtin_nontemporal_store(o, (f32x4*)&att[(rowb + r) * 2048 + j]);
      us4 pk;
      pk.x = f2bf(o[0]); pk.y = f2bf(o[1]); pk.z = f2bf(o[2]); pk.w = f2bf(o[3]);
      *(us4*)&att_s[r][jj] = pk;
    }
    // late LDS write of Wh tile
#pragma unroll
    for (int v = 0; v < 4; ++v)
      *(uint4*)&wh_s[v * 16 + ff][ko] = wreg[v];

    lgkm_barrier();   // publish att_s + wh_s; att nt stores NOT drained
    // PV: acc += att_tile(bf16) @ Wh_tile(bf16); same k-permutation both operands
#pragma unroll
    for (int ks = 0; ks < 4; ++ks) {
      union { us8 u; bf16x8 v; } a0c, b0c, b1c;
      a0c.u = *(const us8*)&att_s[rt + ln][ks * 32 + lg * 8];
      b0c.u = *(const us8*)&wh_s[ft0 * 16 + ln][ks * 32 + lg * 8];
      b1c.u = *(const us8*)&wh_s[ft0 * 16 + 16 + ln][ks * 32 + lg * 8];
      acc0 = __builtin_amdgcn_mfma_f32_16x16x32_bf16(a0c.v, b0c.v, acc0, 0, 0, 0);
      acc1 = __builtin_amdgcn_mfma_f32_16x16x32_bf16(a0c.v, b1c.v, acc1, 0, 0, 0);
    }
    lgkm_barrier();   // reads done before next iter overwrites
  }
  // epilogue: partial sums (no ELU yet). C/D layout: col=lane&15, row=4*(lane>>4)+reg
  float* __restrict__ pp = (jh == 0) ? pp0 : pp1;
#pragma unroll
  for (int q = 0; q < 4; ++q) {
    int r = rt + lg * 4 + q;
    pp[(rowb + r) * 64 + ft0 * 16 + ln]       = acc0[q];
    pp[(rowb + r) * 64 + (ft0 + 1) * 16 + ln] = acc1[q];
  }
}

// ---------------- k3: hout = elu(pp0 + pp1) ----------------
__global__ __launch_bounds__(256)
void k3_elu(const float* __restrict__ pp0, const float* __restrict__ pp1,
            float* __restrict__ hout)
{
  const size_t idx = ((size_t)blockIdx.x * 256 + threadIdx.x) * 4;
  float4 a = *(const float4*)&pp0[idx];
  float4 c = *(const float4*)&pp1[idx];
  float4 o;
  float x;
  x = a.x + c.x; o.x = (x > 0.f) ? x : expm1f(x);
  x = a.y + c.y; o.y = (x > 0.f) ? x : expm1f(x);
  x = a.z + c.z; o.z = (x > 0.f) ? x : expm1f(x);
  x = a.w + c.w; o.w = (x > 0.f) ? x : expm1f(x);
  *(float4*)&hout[idx] = o;
}

extern "C" void kernel_launch(void* const* d_in, const int* in_sizes, int n_in,
                              void* d_out, int out_size, void* d_ws, size_t ws_size,
                              hipStream_t stream)
{
  const float* h   = (const float*)d_in[0];
  const int*   adj = (const int*)d_in[1];
  const float* W   = (const float*)d_in[2];
  const float* a   = (const float*)d_in[3];
  float* hout = (float*)d_out;
  float* att  = hout + (size_t)8 * 2048 * 64;

  char* ws = (char*)d_ws;
  unsigned short* WhT = (unsigned short*)ws;                    // 2 MB
  float* s1 = (float*)(ws + (size_t)(2u << 20));                // 64 KB each
  float* s2 = s1 + 16384;
  float* lr = s2 + 16384;
  unsigned long long* gmask =
      (unsigned long long*)(ws + (size_t)(2u << 20) + 3 * 65536); // 4 MB
  float* pp0 = (float*)(ws + (size_t)(2u << 20) + 3 * 65536 + (4u << 20)); // 4 MB
  float* pp1 = pp0 + (size_t)8 * 2048 * 64;                                // 4 MB

  k0_wh   <<<dim3(32, 8),    256, 0, stream>>>(h, W, a, WhT, s1, s2);
  k1_stats<<<dim3(2048, 8),  256, 0, stream>>>(adj, s1, s2, lr, gmask);
  k2_main <<<dim3(64, 2, 8), 256, 0, stream>>>(gmask, WhT, s1, s2, lr, pp0, pp1, att);
  k3_elu  <<<dim3(1024),     256, 0, stream>>>(pp0, pp1, hout);
}